// Round 1
// baseline (1048.023 us; speedup 1.0000x reference)
//
#include <hip/hip_runtime.h>
#include <hip/hip_bf16.h>

#define N_NODES 12000
#define N_EDGES 384000
#define F_INN   128
#define DLAT    64
#define BN_EPS  1e-4f

typedef __attribute__((ext_vector_type(8))) short bf16x8;
typedef __attribute__((ext_vector_type(4))) float f32x4;

__device__ __forceinline__ float sigmoidf(float x) { return 1.0f / (1.0f + __expf(-x)); }

__device__ __forceinline__ unsigned short f2bf_rne(float x) {
    unsigned u = __float_as_uint(x);
    unsigned r = (u + 0x7fffu + ((u >> 16) & 1u)) >> 16;
    return (unsigned short)r;
}
__device__ __forceinline__ float bf2f(unsigned short h) {
    return __uint_as_float((unsigned)h << 16);
}

// ---------------- CSR build ----------------
__global__ void k_init(int* cnt, int* cur, int n) {
    int i = blockIdx.x * blockDim.x + threadIdx.x;
    if (i < n) { cnt[i] = 0; cur[i] = 0; }
}

__global__ void k_count(const int* dst, int* cnt, int e) {
    int i = blockIdx.x * blockDim.x + threadIdx.x;
    if (i < e) atomicAdd(&cnt[dst[i]], 1);
}

// single-block scan: 1024 threads x 12 elems each (covers 12288 >= 12000)
// also computes dis[i] = rsqrt(deg+1)
__global__ void k_scan(const int* __restrict__ cnt, int* __restrict__ offs,
                       float* __restrict__ dis, int n) {
    __shared__ int wsum[16];
    int tid = threadIdx.x;
    int base = tid * 12;
    int v[12];
    int s = 0;
#pragma unroll
    for (int q = 0; q < 12; q++) {
        int i = base + q;
        v[q] = (i < n) ? cnt[i] : 0;
        s += v[q];
        if (i < n) dis[i] = rsqrtf((float)(v[q] + 1));
    }
    int lane = tid & 63, w = tid >> 6;
    int ps = s;
#pragma unroll
    for (int o = 1; o < 64; o <<= 1) {
        int t2 = __shfl_up(ps, o, 64);
        if (lane >= o) ps += t2;
    }
    if (lane == 63) wsum[w] = ps;
    __syncthreads();
    if (tid == 0) {
        int acc = 0;
        for (int i = 0; i < 16; i++) { int t2 = wsum[i]; wsum[i] = acc; acc += t2; }
    }
    __syncthreads();
    int acc = wsum[w] + ps - s;   // exclusive prefix of this thread's first element
#pragma unroll
    for (int q = 0; q < 12; q++) {
        int i = base + q;
        if (i < n) offs[i] = acc;
        acc += v[q];
        if (i == n - 1) offs[n] = acc;
    }
}

__global__ void k_scatter(const int* src, const int* dst, const int* offs, int* cur,
                          int* ssrc, int e) {
    int i = blockIdx.x * blockDim.x + threadIdx.x;
    if (i < e) {
        int d = dst[i];
        int p = atomicAdd(&cur[d], 1);
        ssrc[offs[d] + p] = src[i];
    }
}

// ---------------- dense X[n,K] @ [Wa|Wb][K,M] -> out[n,M] ----------------
__global__ void k_mm(const float* __restrict__ X, int n, int K,
                     const float* __restrict__ Wa, int Ma,
                     const float* __restrict__ Wb, int Mb,
                     float* __restrict__ out) {
    __shared__ float Wl[8192];
    int M = Ma + Mb;
    for (int idx = threadIdx.x; idx < K * M; idx += blockDim.x) {
        int k = idx / M, m = idx % M;
        Wl[idx] = (m < Ma) ? Wa[k * Ma + m] : Wb[k * Mb + (m - Ma)];
    }
    __syncthreads();
    int rpb = blockDim.x / M;
    int r = blockIdx.x * rpb + threadIdx.x / M;
    int m = threadIdx.x % M;
    if (r >= n) return;
    const float* xr = X + (size_t)r * K;
    float acc = 0.f;
    for (int k = 0; k < K; k++) acc += xr[k] * Wl[k * M + m];
    out[(size_t)r * M + m] = acc;
}

// ---------------- GCN aggregation + bias + sigmoid ----------------
__global__ void k_agg(const float* __restrict__ h, const float* __restrict__ dis,
                      const int* __restrict__ offs, const int* __restrict__ ssrc,
                      const float* __restrict__ ba, const float* __restrict__ bb, int Ma,
                      float* __restrict__ out, int dim, int n) {
    int t = blockIdx.x * blockDim.x + threadIdx.x;
    int node = t / dim;
    if (node >= n) return;
    int f = t - node * dim;
    float di = dis[node];
    float acc = h[(size_t)node * dim + f] * di;
    int e0 = offs[node], e1 = offs[node + 1];
    int j = e0;
    for (; j + 3 < e1; j += 4) {
        int s0 = ssrc[j], s1 = ssrc[j + 1], s2 = ssrc[j + 2], s3 = ssrc[j + 3];
        acc += h[(size_t)s0 * dim + f] * dis[s0];
        acc += h[(size_t)s1 * dim + f] * dis[s1];
        acc += h[(size_t)s2 * dim + f] * dis[s2];
        acc += h[(size_t)s3 * dim + f] * dis[s3];
    }
    for (; j < e1; j++) {
        int s = ssrc[j];
        acc += h[(size_t)s * dim + f] * dis[s];
    }
    float bias = (f < Ma) ? ba[f] : bb[f - Ma];
    out[(size_t)node * dim + f] = sigmoidf(acc * di + bias);
}

// ---------------- BatchNorm stats (two-stage, coalesced) ----------------
#define STATS_BLOCKS 64
__global__ void k_stats1(const float* __restrict__ act, int dim, int n,
                         float* __restrict__ part) {
    int rpb = 256 / dim;                 // rows per iteration per block (4 or 2)
    int c = threadIdx.x % dim;
    int rloc = threadIdx.x / dim;
    float s = 0.f, s2 = 0.f;
    for (int r = blockIdx.x * rpb + rloc; r < n; r += STATS_BLOCKS * rpb) {
        float v = act[(size_t)r * dim + c];
        s += v; s2 += v * v;
    }
    __shared__ float sh[512];
    sh[threadIdx.x] = s; sh[256 + threadIdx.x] = s2;
    __syncthreads();
    if (rloc == 0) {
        for (int q = 1; q < rpb; q++) {
            s += sh[q * dim + c];
            s2 += sh[256 + q * dim + c];
        }
        part[(size_t)(blockIdx.x * dim + c) * 2] = s;
        part[(size_t)(blockIdx.x * dim + c) * 2 + 1] = s2;
    }
}

__global__ void k_stats2(const float* __restrict__ part, int dim, int n,
                         float* __restrict__ mu, float* __restrict__ var) {
    int c = threadIdx.x;
    if (c >= dim) return;
    float s = 0.f, s2 = 0.f;
    for (int q = 0; q < STATS_BLOCKS; q++) {
        s += part[(size_t)(q * dim + c) * 2];
        s2 += part[(size_t)(q * dim + c) * 2 + 1];
    }
    float m = s / n;
    mu[c] = m;
    var[c] = s2 / n - m * m;
}

__global__ void k_bnapply(const float* __restrict__ in, float* __restrict__ out,
                          const float* __restrict__ mu, const float* __restrict__ var,
                          const float* __restrict__ g, const float* __restrict__ be,
                          int dim, size_t total) {
    size_t i = (size_t)blockIdx.x * blockDim.x + threadIdx.x;
    if (i >= total) return;
    int f = (int)(i % dim);
    out[i] = (in[i] - mu[f]) * rsqrtf(var[f] + BN_EPS) * g[f] + be[f];
}

// fused BN(mean)/BN(logstd) + reparameterization.
// Also emits bf16 hi/lo split of z (zh + zl, zl = z - fp32(zh)) for the MFMA
// Gram-matrix kernel, zero-padding rows [n, 12032) so k_apred needs no load guards.
__global__ void k_z(const float* __restrict__ act2, const float* __restrict__ noise,
                    const float* __restrict__ mu, const float* __restrict__ var,
                    const float* __restrict__ gm, const float* __restrict__ bem,
                    const float* __restrict__ gs, const float* __restrict__ bes,
                    float* __restrict__ z, unsigned short* __restrict__ zh,
                    unsigned short* __restrict__ zl, int n) {
    int i = blockIdx.x * blockDim.x + threadIdx.x;
    if (i >= 12032 * 64) return;
    int row = i >> 6, j = i & 63;
    if (row >= n) { zh[i] = 0; zl[i] = 0; return; }
    const float* ar = act2 + (size_t)row * 128;
    float m  = (ar[j]      - mu[j])      * rsqrtf(var[j]      + BN_EPS) * gm[j] + bem[j];
    float ls = (ar[j + 64] - mu[j + 64]) * rsqrtf(var[j + 64] + BN_EPS) * gs[j] + bes[j];
    float zv = noise[i] * __expf(ls) + m;
    z[i] = zv;
    unsigned short h = f2bf_rne(zv);
    zh[i] = h;
    zl[i] = f2bf_rne(zv - bf2f(h));
}

// ---------------- decoder MLP, 16 rows per block ----------------
__global__ void k_dec(const float* __restrict__ z,
                      const float* __restrict__ W1, const float* __restrict__ B1,
                      const float* __restrict__ W2, const float* __restrict__ B2,
                      float* __restrict__ out, int n) {
    __shared__ float w1[64 * 64];
    __shared__ float w2[64 * 128];
    __shared__ float zl[16 * 64];
    __shared__ float hl[16 * 64];
    int t = threadIdx.x;
    int row0 = blockIdx.x * 16;
    {
        const float4* W14 = (const float4*)W1;
        const float4* W24 = (const float4*)W2;
        for (int i = t; i < 1024; i += 256) ((float4*)w1)[i] = W14[i];
        for (int i = t; i < 2048; i += 256) ((float4*)w2)[i] = W24[i];
        ((float4*)zl)[t] = ((const float4*)(z + (size_t)row0 * 64))[t];
    }
    __syncthreads();
    {
        int hc = t & 63, rg = t >> 6;      // 4 rows per thread
        float a0 = B1[hc], a1 = a0, a2 = a0, a3 = a0;
        int rb = rg * 4;
        for (int k = 0; k < 64; k++) {
            float wv = w1[k * 64 + hc];
            a0 += zl[(rb + 0) * 64 + k] * wv;
            a1 += zl[(rb + 1) * 64 + k] * wv;
            a2 += zl[(rb + 2) * 64 + k] * wv;
            a3 += zl[(rb + 3) * 64 + k] * wv;
        }
        hl[(rb + 0) * 64 + hc] = a0 > 0.f ? a0 : 0.01f * a0;
        hl[(rb + 1) * 64 + hc] = a1 > 0.f ? a1 : 0.01f * a1;
        hl[(rb + 2) * 64 + hc] = a2 > 0.f ? a2 : 0.01f * a2;
        hl[(rb + 3) * 64 + hc] = a3 > 0.f ? a3 : 0.01f * a3;
    }
    __syncthreads();
    {
        int oc = t & 127, rg = t >> 7;     // 8 rows per thread
        float o[8];
#pragma unroll
        for (int i = 0; i < 8; i++) o[i] = B2[oc];
        int rb = rg * 8;
        for (int k = 0; k < 64; k++) {
            float wv = w2[k * 128 + oc];
#pragma unroll
            for (int i = 0; i < 8; i++) o[i] += hl[(rb + i) * 64 + k] * wv;
        }
#pragma unroll
        for (int i = 0; i < 8; i++)
            out[(size_t)(row0 + rb + i) * 128 + oc] = o[i];
    }
}

// ---------------- A_pred = sigmoid(z @ z^T) via bf16 hi/lo split MFMA ----------------
// A ~= zh*zh^T + zh*zl^T + zl*zh^T (zl*zl^T term ~2^-18 relative, dropped).
// 128x128 tile per block, 4 waves in 2x2, each wave a 64x64 sub-tile of 4x4
// mfma_f32_16x16x32_bf16 fragments. Fragments are gathered directly from the
// L2-resident zh/zl (no LDS). Gram symmetry: A- and B-fragments use the same
// (lane&15 -> row, (lane>>4)*8 -> k) packing, so any consistent k-permutation
// is correct; only the C/D layout (col=lane&15, row=(lane>>4)*4+reg) matters.
#define TN2 94   // ceil(12000/128)
__global__ __launch_bounds__(256) void k_apred(const unsigned short* __restrict__ zh,
                                               const unsigned short* __restrict__ zl,
                                               float* __restrict__ out, int n) {
    int b = blockIdx.x;
    // decode triangular (bi <= bj)
    float ff = (float)(2 * TN2 + 1);
    int bi = (int)((ff - sqrtf(ff * ff - 8.0f * (float)b)) * 0.5f);
    while (bi > 0 && b < bi * TN2 - bi * (bi - 1) / 2) bi--;
    while (b >= (bi + 1) * TN2 - (bi + 1) * bi / 2) bi++;
    int bj = bi + (b - (bi * TN2 - bi * (bi - 1) / 2));
    int i0 = bi * 128, j0 = bj * 128;

    int t = threadIdx.x;
    int wave = t >> 6, lane = t & 63;
    int wr = wave >> 1, wc = wave & 1;
    int lrow = lane & 15;   // row (A) / col (B) within fragment
    int kg   = lane >> 4;   // k-group 0..3

    int arow0 = i0 + wr * 64;   // wave's D-rows base (A-operand rows)
    int brow0 = j0 + wc * 64;   // wave's D-cols base (B-operand rows of z)

    f32x4 acc[4][4] = {};

#pragma unroll
    for (int kc = 0; kc < 2; kc++) {
        int koff = kc * 32 + kg * 8;
        bf16x8 ah[4], al[4], bh[4], bl[4];
#pragma unroll
        for (int f = 0; f < 4; f++) {
            size_t aoff = (size_t)(arow0 + f * 16 + lrow) * 64 + koff;
            ah[f] = *(const bf16x8*)(zh + aoff);
            al[f] = *(const bf16x8*)(zl + aoff);
            size_t boff = (size_t)(brow0 + f * 16 + lrow) * 64 + koff;
            bh[f] = *(const bf16x8*)(zh + boff);
            bl[f] = *(const bf16x8*)(zl + boff);
        }
#pragma unroll
        for (int fi = 0; fi < 4; fi++)
#pragma unroll
            for (int fj = 0; fj < 4; fj++) {
                acc[fi][fj] = __builtin_amdgcn_mfma_f32_16x16x32_bf16(
                    ah[fi], bh[fj], acc[fi][fj], 0, 0, 0);
                acc[fi][fj] = __builtin_amdgcn_mfma_f32_16x16x32_bf16(
                    ah[fi], bl[fj], acc[fi][fj], 0, 0, 0);
                acc[fi][fj] = __builtin_amdgcn_mfma_f32_16x16x32_bf16(
                    al[fi], bh[fj], acc[fi][fj], 0, 0, 0);
            }
    }

    // sigmoid once, in-register
#pragma unroll
    for (int fi = 0; fi < 4; fi++)
#pragma unroll
        for (int fj = 0; fj < 4; fj++)
#pragma unroll
            for (int q = 0; q < 4; q++)
                acc[fi][fj][q] = sigmoidf(acc[fi][fj][q]);

    // normal tile write: row = arow0 + fi*16 + kg*4 + q, col = brow0 + fj*16 + lrow
#pragma unroll
    for (int fi = 0; fi < 4; fi++) {
#pragma unroll
        for (int q = 0; q < 4; q++) {
            int r = arow0 + fi * 16 + kg * 4 + q;
            if (r < n) {
#pragma unroll
                for (int fj = 0; fj < 4; fj++) {
                    int c = brow0 + fj * 16 + lrow;
                    if (c < n) out[(size_t)r * n + c] = acc[fi][fj][q];
                }
            }
        }
    }
    // mirrored tile write (transpose)
    if (bi != bj) {
#pragma unroll
        for (int fj = 0; fj < 4; fj++) {
            int c = brow0 + fj * 16 + lrow;
            if (c < n) {
#pragma unroll
                for (int fi = 0; fi < 4; fi++) {
#pragma unroll
                    for (int q = 0; q < 4; q++) {
                        int r = arow0 + fi * 16 + kg * 4 + q;
                        if (r < n) out[(size_t)c * n + r] = acc[fi][fj][q];
                    }
                }
            }
        }
    }
}

extern "C" void kernel_launch(void* const* d_in, const int* in_sizes, int n_in,
                              void* d_out, int out_size, void* d_ws, size_t ws_size,
                              hipStream_t stream) {
    const float* x     = (const float*)d_in[0];
    const int*   src   = (const int*)d_in[1];
    const int*   dst   = (const int*)d_in[2];
    const float* noise = (const float*)d_in[4];
    const float* W0  = (const float*)d_in[5];
    const float* b0  = (const float*)d_in[6];
    const float* g0  = (const float*)d_in[7];
    const float* be0 = (const float*)d_in[8];
    const float* Wm  = (const float*)d_in[9];
    const float* bm  = (const float*)d_in[10];
    const float* gm  = (const float*)d_in[11];
    const float* bem = (const float*)d_in[12];
    const float* Ws  = (const float*)d_in[13];
    const float* bs  = (const float*)d_in[14];
    const float* gs  = (const float*)d_in[15];
    const float* bes = (const float*)d_in[16];
    const float* Dw1 = (const float*)d_in[17];
    const float* Db1 = (const float*)d_in[18];
    const float* Dw2 = (const float*)d_in[19];
    const float* Db2 = (const float*)d_in[20];
    float* out = (float*)d_out;

    const int n = N_NODES, e = N_EDGES;

    // workspace layout (4-byte words)
    int*   cnt  = (int*)d_ws;                       // 12000
    int*   offs = (int*)d_ws + 12032;               // 12001
    int*   cur  = (int*)d_ws + 24064;               // 12000
    int*   ssrc = (int*)d_ws + 36096;               // 384000
    float* dis  = (float*)d_ws + 420096;            // 12000
    float* mu   = (float*)d_ws + 432128;            // 128
    float* var  = (float*)d_ws + 432384;            // 128
    float* part = (float*)d_ws + 432640;            // 64*128*2 = 16384
    float* bufA = (float*)d_ws + 449024;            // [N,128]
    float* bufB = bufA + (size_t)N_NODES * 128;     // [N,128]
    float* zbuf = bufB;
    // bf16 hi/lo split of z, padded to 12032 rows (16B-aligned)
    unsigned short* zhbuf = (unsigned short*)((float*)d_ws + 3521024); // 12032*64 ushort
    unsigned short* zlbuf = (unsigned short*)((float*)d_ws + 3906048); // 12032*64 ushort

    // CSR build
    k_init<<<(n + 255) / 256, 256, 0, stream>>>(cnt, cur, n);
    k_count<<<(e + 255) / 256, 256, 0, stream>>>(dst, cnt, e);
    k_scan<<<1, 1024, 0, stream>>>(cnt, offs, dis, n);
    k_scatter<<<(e + 255) / 256, 256, 0, stream>>>(src, dst, offs, cur, ssrc, e);

    // layer 1
    k_mm<<<n / 4, 256, 0, stream>>>(x, n, F_INN, W0, DLAT, nullptr, 0, bufA);
    k_agg<<<(n * DLAT) / 256, 256, 0, stream>>>(bufA, dis, offs, ssrc, b0, nullptr, DLAT,
                                                bufB, DLAT, n);
    k_stats1<<<STATS_BLOCKS, 256, 0, stream>>>(bufB, DLAT, n, part);
    k_stats2<<<1, 64, 0, stream>>>(part, DLAT, n, mu, var);
    k_bnapply<<<(n * DLAT) / 256, 256, 0, stream>>>(bufB, bufA, mu, var, g0, be0, DLAT,
                                                    (size_t)n * DLAT);

    // layers 2+3 fused
    k_mm<<<n / 2, 256, 0, stream>>>(bufA, n, DLAT, Wm, DLAT, Ws, DLAT, bufB);
    k_agg<<<(n * 128) / 256, 256, 0, stream>>>(bufB, dis, offs, ssrc, bm, bs, DLAT,
                                               bufA, 128, n);
    k_stats1<<<STATS_BLOCKS, 256, 0, stream>>>(bufA, 128, n, part);
    k_stats2<<<1, 128, 0, stream>>>(part, 128, n, mu, var);

    // BN + reparameterize -> z (fp32) + zh/zl (bf16 split, pad rows zeroed)
    k_z<<<(12032 * 64) / 256, 256, 0, stream>>>(bufA, noise, mu, var, gm, bem, gs, bes,
                                                zbuf, zhbuf, zlbuf, n);

    // decoder
    k_dec<<<n / 16, 256, 0, stream>>>(zbuf, Dw1, Db1, Dw2, Db2, out, n);

    // A_pred (symmetric, MFMA)
    k_apred<<<TN2 * (TN2 + 1) / 2, 256, 0, stream>>>(zhbuf, zlbuf,
                                                     out + (size_t)n * F_INN, n);
}

// Round 2
// 952.635 us; speedup vs baseline: 1.1001x; 1.1001x over previous
//
#include <hip/hip_runtime.h>
#include <hip/hip_bf16.h>

#define N_NODES 12000
#define N_EDGES 384000
#define F_INN   128
#define DLAT    64
#define BN_EPS  1e-4f

typedef __attribute__((ext_vector_type(8))) short bf16x8;
typedef __attribute__((ext_vector_type(4))) float f32x4;

__device__ __forceinline__ float sigmoidf(float x) { return 1.0f / (1.0f + __expf(-x)); }

__device__ __forceinline__ unsigned short f2bf_rne(float x) {
    unsigned u = __float_as_uint(x);
    unsigned r = (u + 0x7fffu + ((u >> 16) & 1u)) >> 16;
    return (unsigned short)r;
}
__device__ __forceinline__ float bf2f(unsigned short h) {
    return __uint_as_float((unsigned)h << 16);
}

// ---------------- CSR build ----------------
__global__ void k_init(int* cnt, int* cur, int n) {
    int i = blockIdx.x * blockDim.x + threadIdx.x;
    if (i < n) { cnt[i] = 0; cur[i] = 0; }
}

__global__ void k_count(const int* dst, int* cnt, int e) {
    int i = blockIdx.x * blockDim.x + threadIdx.x;
    if (i < e) atomicAdd(&cnt[dst[i]], 1);
}

// single-block scan: 1024 threads x 12 elems each (covers 12288 >= 12000)
// also computes dis[i] = rsqrt(deg+1)
__global__ void k_scan(const int* __restrict__ cnt, int* __restrict__ offs,
                       float* __restrict__ dis, int n) {
    __shared__ int wsum[16];
    int tid = threadIdx.x;
    int base = tid * 12;
    int v[12];
    int s = 0;
#pragma unroll
    for (int q = 0; q < 12; q++) {
        int i = base + q;
        v[q] = (i < n) ? cnt[i] : 0;
        s += v[q];
        if (i < n) dis[i] = rsqrtf((float)(v[q] + 1));
    }
    int lane = tid & 63, w = tid >> 6;
    int ps = s;
#pragma unroll
    for (int o = 1; o < 64; o <<= 1) {
        int t2 = __shfl_up(ps, o, 64);
        if (lane >= o) ps += t2;
    }
    if (lane == 63) wsum[w] = ps;
    __syncthreads();
    if (tid == 0) {
        int acc = 0;
        for (int i = 0; i < 16; i++) { int t2 = wsum[i]; wsum[i] = acc; acc += t2; }
    }
    __syncthreads();
    int acc = wsum[w] + ps - s;   // exclusive prefix of this thread's first element
#pragma unroll
    for (int q = 0; q < 12; q++) {
        int i = base + q;
        if (i < n) offs[i] = acc;
        acc += v[q];
        if (i == n - 1) offs[n] = acc;
    }
}

__global__ void k_scatter(const int* src, const int* dst, const int* offs, int* cur,
                          int* ssrc, int e) {
    int i = blockIdx.x * blockDim.x + threadIdx.x;
    if (i < e) {
        int d = dst[i];
        int p = atomicAdd(&cur[d], 1);
        ssrc[offs[d] + p] = src[i];
    }
}

// ---------------- dense X[n,K] @ [Wa|Wb][K,M] -> out[n,M] ----------------
__global__ void k_mm(const float* __restrict__ X, int n, int K,
                     const float* __restrict__ Wa, int Ma,
                     const float* __restrict__ Wb, int Mb,
                     float* __restrict__ out) {
    __shared__ float Wl[8192];
    int M = Ma + Mb;
    for (int idx = threadIdx.x; idx < K * M; idx += blockDim.x) {
        int k = idx / M, m = idx % M;
        Wl[idx] = (m < Ma) ? Wa[k * Ma + m] : Wb[k * Mb + (m - Ma)];
    }
    __syncthreads();
    int rpb = blockDim.x / M;
    int r = blockIdx.x * rpb + threadIdx.x / M;
    int m = threadIdx.x % M;
    if (r >= n) return;
    const float* xr = X + (size_t)r * K;
    float acc = 0.f;
    for (int k = 0; k < K; k++) acc += xr[k] * Wl[k * M + m];
    out[(size_t)r * M + m] = acc;
}

// ---------------- GCN aggregation + bias + sigmoid ----------------
__global__ void k_agg(const float* __restrict__ h, const float* __restrict__ dis,
                      const int* __restrict__ offs, const int* __restrict__ ssrc,
                      const float* __restrict__ ba, const float* __restrict__ bb, int Ma,
                      float* __restrict__ out, int dim, int n) {
    int t = blockIdx.x * blockDim.x + threadIdx.x;
    int node = t / dim;
    if (node >= n) return;
    int f = t - node * dim;
    float di = dis[node];
    float acc = h[(size_t)node * dim + f] * di;
    int e0 = offs[node], e1 = offs[node + 1];
    int j = e0;
    for (; j + 3 < e1; j += 4) {
        int s0 = ssrc[j], s1 = ssrc[j + 1], s2 = ssrc[j + 2], s3 = ssrc[j + 3];
        acc += h[(size_t)s0 * dim + f] * dis[s0];
        acc += h[(size_t)s1 * dim + f] * dis[s1];
        acc += h[(size_t)s2 * dim + f] * dis[s2];
        acc += h[(size_t)s3 * dim + f] * dis[s3];
    }
    for (; j < e1; j++) {
        int s = ssrc[j];
        acc += h[(size_t)s * dim + f] * dis[s];
    }
    float bias = (f < Ma) ? ba[f] : bb[f - Ma];
    out[(size_t)node * dim + f] = sigmoidf(acc * di + bias);
}

// ---------------- BatchNorm stats (two-stage, coalesced) ----------------
#define STATS_BLOCKS 64
__global__ void k_stats1(const float* __restrict__ act, int dim, int n,
                         float* __restrict__ part) {
    int rpb = 256 / dim;                 // rows per iteration per block (4 or 2)
    int c = threadIdx.x % dim;
    int rloc = threadIdx.x / dim;
    float s = 0.f, s2 = 0.f;
    for (int r = blockIdx.x * rpb + rloc; r < n; r += STATS_BLOCKS * rpb) {
        float v = act[(size_t)r * dim + c];
        s += v; s2 += v * v;
    }
    __shared__ float sh[512];
    sh[threadIdx.x] = s; sh[256 + threadIdx.x] = s2;
    __syncthreads();
    if (rloc == 0) {
        for (int q = 1; q < rpb; q++) {
            s += sh[q * dim + c];
            s2 += sh[256 + q * dim + c];
        }
        part[(size_t)(blockIdx.x * dim + c) * 2] = s;
        part[(size_t)(blockIdx.x * dim + c) * 2 + 1] = s2;
    }
}

__global__ void k_stats2(const float* __restrict__ part, int dim, int n,
                         float* __restrict__ mu, float* __restrict__ var) {
    int c = threadIdx.x;
    if (c >= dim) return;
    float s = 0.f, s2 = 0.f;
    for (int q = 0; q < STATS_BLOCKS; q++) {
        s += part[(size_t)(q * dim + c) * 2];
        s2 += part[(size_t)(q * dim + c) * 2 + 1];
    }
    float m = s / n;
    mu[c] = m;
    var[c] = s2 / n - m * m;
}

__global__ void k_bnapply(const float* __restrict__ in, float* __restrict__ out,
                          const float* __restrict__ mu, const float* __restrict__ var,
                          const float* __restrict__ g, const float* __restrict__ be,
                          int dim, size_t total) {
    size_t i = (size_t)blockIdx.x * blockDim.x + threadIdx.x;
    if (i >= total) return;
    int f = (int)(i % dim);
    out[i] = (in[i] - mu[f]) * rsqrtf(var[f] + BN_EPS) * g[f] + be[f];
}

// fused BN(mean)/BN(logstd) + reparameterization.
// Also emits bf16 hi/lo split of z (zh + zl, zl = z - fp32(zh)) for the MFMA
// Gram-matrix kernel, zero-padding rows [n, 12032) so k_apred needs no load guards.
__global__ void k_z(const float* __restrict__ act2, const float* __restrict__ noise,
                    const float* __restrict__ mu, const float* __restrict__ var,
                    const float* __restrict__ gm, const float* __restrict__ bem,
                    const float* __restrict__ gs, const float* __restrict__ bes,
                    float* __restrict__ z, unsigned short* __restrict__ zh,
                    unsigned short* __restrict__ zl, int n) {
    int i = blockIdx.x * blockDim.x + threadIdx.x;
    if (i >= 12032 * 64) return;
    int row = i >> 6, j = i & 63;
    if (row >= n) { zh[i] = 0; zl[i] = 0; return; }
    const float* ar = act2 + (size_t)row * 128;
    float m  = (ar[j]      - mu[j])      * rsqrtf(var[j]      + BN_EPS) * gm[j] + bem[j];
    float ls = (ar[j + 64] - mu[j + 64]) * rsqrtf(var[j + 64] + BN_EPS) * gs[j] + bes[j];
    float zv = noise[i] * __expf(ls) + m;
    z[i] = zv;
    unsigned short h = f2bf_rne(zv);
    zh[i] = h;
    zl[i] = f2bf_rne(zv - bf2f(h));
}

// ---------------- decoder MLP, 16 rows per block ----------------
__global__ void k_dec(const float* __restrict__ z,
                      const float* __restrict__ W1, const float* __restrict__ B1,
                      const float* __restrict__ W2, const float* __restrict__ B2,
                      float* __restrict__ out, int n) {
    __shared__ float w1[64 * 64];
    __shared__ float w2[64 * 128];
    __shared__ float zl[16 * 64];
    __shared__ float hl[16 * 64];
    int t = threadIdx.x;
    int row0 = blockIdx.x * 16;
    {
        const float4* W14 = (const float4*)W1;
        const float4* W24 = (const float4*)W2;
        for (int i = t; i < 1024; i += 256) ((float4*)w1)[i] = W14[i];
        for (int i = t; i < 2048; i += 256) ((float4*)w2)[i] = W24[i];
        ((float4*)zl)[t] = ((const float4*)(z + (size_t)row0 * 64))[t];
    }
    __syncthreads();
    {
        int hc = t & 63, rg = t >> 6;      // 4 rows per thread
        float a0 = B1[hc], a1 = a0, a2 = a0, a3 = a0;
        int rb = rg * 4;
        for (int k = 0; k < 64; k++) {
            float wv = w1[k * 64 + hc];
            a0 += zl[(rb + 0) * 64 + k] * wv;
            a1 += zl[(rb + 1) * 64 + k] * wv;
            a2 += zl[(rb + 2) * 64 + k] * wv;
            a3 += zl[(rb + 3) * 64 + k] * wv;
        }
        hl[(rb + 0) * 64 + hc] = a0 > 0.f ? a0 : 0.01f * a0;
        hl[(rb + 1) * 64 + hc] = a1 > 0.f ? a1 : 0.01f * a1;
        hl[(rb + 2) * 64 + hc] = a2 > 0.f ? a2 : 0.01f * a2;
        hl[(rb + 3) * 64 + hc] = a3 > 0.f ? a3 : 0.01f * a3;
    }
    __syncthreads();
    {
        int oc = t & 127, rg = t >> 7;     // 8 rows per thread
        float o[8];
#pragma unroll
        for (int i = 0; i < 8; i++) o[i] = B2[oc];
        int rb = rg * 8;
        for (int k = 0; k < 64; k++) {
            float wv = w2[k * 128 + oc];
#pragma unroll
            for (int i = 0; i < 8; i++) o[i] += hl[(rb + i) * 64 + k] * wv;
        }
#pragma unroll
        for (int i = 0; i < 8; i++)
            out[(size_t)(row0 + rb + i) * 128 + oc] = o[i];
    }
}

// ---------------- A_pred = sigmoid(z @ z^T) via bf16 hi/lo split MFMA ----------------
// Full 94x94 block grid (no triangular mirror): every store is row-major
// coalesced. Tiles staged in LDS with c16 ^= (row&7) XOR swizzle on 16B units
// so ds_write_b128 / ds_read_b128 are conflict-free. A/B fragments use the
// same (lane&15 -> row, (lane>>4)*8 -> k) packing (Gram symmetry); C/D layout:
// col = lane&15, row = (lane>>4)*4 + reg.
#define TN2 94   // ceil(12000/128); 94*128 = 12032 = padded row count
__global__ __launch_bounds__(256, 2) void k_apred(const unsigned short* __restrict__ zh,
                                                  const unsigned short* __restrict__ zl,
                                                  float* __restrict__ out, int n) {
    __shared__ __align__(16) unsigned short si_h[128 * 64];
    __shared__ __align__(16) unsigned short si_l[128 * 64];
    __shared__ __align__(16) unsigned short sj_h[128 * 64];
    __shared__ __align__(16) unsigned short sj_l[128 * 64];

    int bj = blockIdx.x, bi = blockIdx.y;
    int i0 = bi * 128, j0 = bj * 128;
    int t = threadIdx.x;

    // stage one 128x64 bf16 tile (128 rows x 128 B) into LDS, XOR-swizzled.
    // 1024 16B-units; thread t handles units q*256+t -> perfectly coalesced
    // global reads, conflict-free LDS writes.
    auto stage = [&](const unsigned short* __restrict__ g, unsigned short* s, int row0) {
#pragma unroll
        for (int q = 0; q < 4; q++) {
            int u = q * 256 + t;
            int row = u >> 3, c16 = u & 7;
            int c16s = c16 ^ (row & 7);
            *(float4*)((char*)s + row * 128 + c16s * 16) =
                *(const float4*)(g + (size_t)(row0 + row) * 64 + c16 * 8);
        }
    };
    stage(zh, si_h, i0);
    stage(zl, si_l, i0);
    stage(zh, sj_h, j0);
    stage(zl, sj_l, j0);
    __syncthreads();

    int wave = t >> 6, lane = t & 63;
    int wr = wave >> 1, wc = wave & 1;
    int lrow = lane & 15;   // row (A) / col (B) within fragment
    int kg   = lane >> 4;   // k-group 0..3

    auto frag = [&](const unsigned short* s, int tr, int kc) -> bf16x8 {
        int c16s = (kc * 4 + kg) ^ (tr & 7);
        return *(const bf16x8*)((const char*)s + tr * 128 + c16s * 16);
    };

    f32x4 acc[4][4] = {};

#pragma unroll
    for (int kc = 0; kc < 2; kc++) {
        bf16x8 ah[4], al[4], bh[4], bl[4];
#pragma unroll
        for (int f = 0; f < 4; f++) {
            int tra = wr * 64 + f * 16 + lrow;
            ah[f] = frag(si_h, tra, kc);
            al[f] = frag(si_l, tra, kc);
            int trb = wc * 64 + f * 16 + lrow;
            bh[f] = frag(sj_h, trb, kc);
            bl[f] = frag(sj_l, trb, kc);
        }
#pragma unroll
        for (int fi = 0; fi < 4; fi++)
#pragma unroll
            for (int fj = 0; fj < 4; fj++) {
                acc[fi][fj] = __builtin_amdgcn_mfma_f32_16x16x32_bf16(
                    ah[fi], bh[fj], acc[fi][fj], 0, 0, 0);
                acc[fi][fj] = __builtin_amdgcn_mfma_f32_16x16x32_bf16(
                    ah[fi], bl[fj], acc[fi][fj], 0, 0, 0);
                acc[fi][fj] = __builtin_amdgcn_mfma_f32_16x16x32_bf16(
                    al[fi], bh[fj], acc[fi][fj], 0, 0, 0);
            }
    }

    // sigmoid once, in-register
#pragma unroll
    for (int fi = 0; fi < 4; fi++)
#pragma unroll
        for (int fj = 0; fj < 4; fj++)
#pragma unroll
            for (int q = 0; q < 4; q++)
                acc[fi][fj][q] = sigmoidf(acc[fi][fj][q]);

    // row-major coalesced store: row = i0+wr*64+fi*16+kg*4+q (uniform per
    // instruction within each 16-lane group), col = j0+wc*64+fj*16+lrow
    // (16 consecutive floats per 16-lane group -> 64B segments).
    int colb = j0 + wc * 64;
#pragma unroll
    for (int fi = 0; fi < 4; fi++) {
#pragma unroll
        for (int q = 0; q < 4; q++) {
            int r = i0 + wr * 64 + fi * 16 + kg * 4 + q;
            if (r < n) {
                float* orow = out + (size_t)r * n + colb;
#pragma unroll
                for (int fj = 0; fj < 4; fj++) {
                    int c = fj * 16 + lrow;
                    if (colb + c < n) orow[c] = acc[fi][fj][q];
                }
            }
        }
    }
}

extern "C" void kernel_launch(void* const* d_in, const int* in_sizes, int n_in,
                              void* d_out, int out_size, void* d_ws, size_t ws_size,
                              hipStream_t stream) {
    const float* x     = (const float*)d_in[0];
    const int*   src   = (const int*)d_in[1];
    const int*   dst   = (const int*)d_in[2];
    const float* noise = (const float*)d_in[4];
    const float* W0  = (const float*)d_in[5];
    const float* b0  = (const float*)d_in[6];
    const float* g0  = (const float*)d_in[7];
    const float* be0 = (const float*)d_in[8];
    const float* Wm  = (const float*)d_in[9];
    const float* bm  = (const float*)d_in[10];
    const float* gm  = (const float*)d_in[11];
    const float* bem = (const float*)d_in[12];
    const float* Ws  = (const float*)d_in[13];
    const float* bs  = (const float*)d_in[14];
    const float* gs  = (const float*)d_in[15];
    const float* bes = (const float*)d_in[16];
    const float* Dw1 = (const float*)d_in[17];
    const float* Db1 = (const float*)d_in[18];
    const float* Dw2 = (const float*)d_in[19];
    const float* Db2 = (const float*)d_in[20];
    float* out = (float*)d_out;

    const int n = N_NODES, e = N_EDGES;

    // workspace layout (4-byte words)
    int*   cnt  = (int*)d_ws;                       // 12000
    int*   offs = (int*)d_ws + 12032;               // 12001
    int*   cur  = (int*)d_ws + 24064;               // 12000
    int*   ssrc = (int*)d_ws + 36096;               // 384000
    float* dis  = (float*)d_ws + 420096;            // 12000
    float* mu   = (float*)d_ws + 432128;            // 128
    float* var  = (float*)d_ws + 432384;            // 128
    float* part = (float*)d_ws + 432640;            // 64*128*2 = 16384
    float* bufA = (float*)d_ws + 449024;            // [N,128]
    float* bufB = bufA + (size_t)N_NODES * 128;     // [N,128]
    float* zbuf = bufB;
    // bf16 hi/lo split of z, padded to 12032 rows (16B-aligned)
    unsigned short* zhbuf = (unsigned short*)((float*)d_ws + 3521024); // 12032*64 ushort
    unsigned short* zlbuf = (unsigned short*)((float*)d_ws + 3906048); // 12032*64 ushort

    // CSR build
    k_init<<<(n + 255) / 256, 256, 0, stream>>>(cnt, cur, n);
    k_count<<<(e + 255) / 256, 256, 0, stream>>>(dst, cnt, e);
    k_scan<<<1, 1024, 0, stream>>>(cnt, offs, dis, n);
    k_scatter<<<(e + 255) / 256, 256, 0, stream>>>(src, dst, offs, cur, ssrc, e);

    // layer 1
    k_mm<<<n / 4, 256, 0, stream>>>(x, n, F_INN, W0, DLAT, nullptr, 0, bufA);
    k_agg<<<(n * DLAT) / 256, 256, 0, stream>>>(bufA, dis, offs, ssrc, b0, nullptr, DLAT,
                                                bufB, DLAT, n);
    k_stats1<<<STATS_BLOCKS, 256, 0, stream>>>(bufB, DLAT, n, part);
    k_stats2<<<1, 64, 0, stream>>>(part, DLAT, n, mu, var);
    k_bnapply<<<(n * DLAT) / 256, 256, 0, stream>>>(bufB, bufA, mu, var, g0, be0, DLAT,
                                                    (size_t)n * DLAT);

    // layers 2+3 fused
    k_mm<<<n / 2, 256, 0, stream>>>(bufA, n, DLAT, Wm, DLAT, Ws, DLAT, bufB);
    k_agg<<<(n * 128) / 256, 256, 0, stream>>>(bufB, dis, offs, ssrc, bm, bs, DLAT,
                                               bufA, 128, n);
    k_stats1<<<STATS_BLOCKS, 256, 0, stream>>>(bufA, 128, n, part);
    k_stats2<<<1, 128, 0, stream>>>(part, 128, n, mu, var);

    // BN + reparameterize -> z (fp32) + zh/zl (bf16 split, pad rows zeroed)
    k_z<<<(12032 * 64) / 256, 256, 0, stream>>>(bufA, noise, mu, var, gm, bem, gs, bes,
                                                zbuf, zhbuf, zlbuf, n);

    // decoder
    k_dec<<<n / 16, 256, 0, stream>>>(zbuf, Dw1, Db1, Dw2, Db2, out, n);

    // A_pred (full grid, all-coalesced stores)
    {
        dim3 grid(TN2, TN2);
        k_apred<<<grid, 256, 0, stream>>>(zhbuf, zlbuf, out + (size_t)n * F_INN, n);
    }
}

// Round 3
// 902.213 us; speedup vs baseline: 1.1616x; 1.0559x over previous
//
#include <hip/hip_runtime.h>
#include <hip/hip_bf16.h>

#define N_NODES 12000
#define N_EDGES 384000
#define F_INN   128
#define DLAT    64
#define BN_EPS  1e-4f

typedef __attribute__((ext_vector_type(8))) short bf16x8;
typedef __attribute__((ext_vector_type(4))) float f32x4;

__device__ __forceinline__ float sigmoidf(float x) { return 1.0f / (1.0f + __expf(-x)); }

__device__ __forceinline__ unsigned short f2bf_rne(float x) {
    unsigned u = __float_as_uint(x);
    unsigned r = (u + 0x7fffu + ((u >> 16) & 1u)) >> 16;
    return (unsigned short)r;
}
__device__ __forceinline__ float bf2f(unsigned short h) {
    return __uint_as_float((unsigned)h << 16);
}

// ---------------- init: counters, stat accumulators, zh/zl pad rows ----------------
__global__ void k_init(int* cnt, int* cur, float* sA, float* sB,
                       unsigned short* zh, unsigned short* zl, int n) {
    int i = blockIdx.x * blockDim.x + threadIdx.x;
    if (i < n) { cnt[i] = 0; cur[i] = 0; }
    if (i < 128) sA[i] = 0.f;
    if (i < 256) sB[i] = 0.f;
    if (i < 2048) {   // pad rows 12000..12031 of zh/zl (32 rows x 64)
        zh[12000 * 64 + i] = 0;
        zl[12000 * 64 + i] = 0;
    }
}

__global__ void k_count(const int* dst, int* cnt, int e) {
    int i = blockIdx.x * blockDim.x + threadIdx.x;
    if (i < e) atomicAdd(&cnt[dst[i]], 1);
}

// single-block scan: 1024 threads x 12 elems each (covers 12288 >= 12000)
// also computes dis[i] = rsqrt(deg+1)
__global__ void k_scan(const int* __restrict__ cnt, int* __restrict__ offs,
                       float* __restrict__ dis, int n) {
    __shared__ int wsum[16];
    int tid = threadIdx.x;
    int base = tid * 12;
    int v[12];
    int s = 0;
#pragma unroll
    for (int q = 0; q < 12; q++) {
        int i = base + q;
        v[q] = (i < n) ? cnt[i] : 0;
        s += v[q];
        if (i < n) dis[i] = rsqrtf((float)(v[q] + 1));
    }
    int lane = tid & 63, w = tid >> 6;
    int ps = s;
#pragma unroll
    for (int o = 1; o < 64; o <<= 1) {
        int t2 = __shfl_up(ps, o, 64);
        if (lane >= o) ps += t2;
    }
    if (lane == 63) wsum[w] = ps;
    __syncthreads();
    if (tid == 0) {
        int acc = 0;
        for (int i = 0; i < 16; i++) { int t2 = wsum[i]; wsum[i] = acc; acc += t2; }
    }
    __syncthreads();
    int acc = wsum[w] + ps - s;   // exclusive prefix of this thread's first element
#pragma unroll
    for (int q = 0; q < 12; q++) {
        int i = base + q;
        if (i < n) offs[i] = acc;
        acc += v[q];
        if (i == n - 1) offs[n] = acc;
    }
}

__global__ void k_scatter(const int* src, const int* dst, const int* offs, int* cur,
                          int* ssrc, int e) {
    int i = blockIdx.x * blockDim.x + threadIdx.x;
    if (i < e) {
        int d = dst[i];
        int p = atomicAdd(&cur[d], 1);
        ssrc[offs[d] + p] = src[i];
    }
}

// ---------------- layer-1 GEMM: X[n,128] @ W0[128,64] -> out[n,64] ----------------
__global__ void k_mm(const float* __restrict__ X, int n, int K,
                     const float* __restrict__ Wa, int Ma,
                     const float* __restrict__ Wb, int Mb,
                     float* __restrict__ out) {
    __shared__ float Wl[8192];
    int M = Ma + Mb;
    for (int idx = threadIdx.x; idx < K * M; idx += blockDim.x) {
        int k = idx / M, m = idx % M;
        Wl[idx] = (m < Ma) ? Wa[k * Ma + m] : Wb[k * Mb + (m - Ma)];
    }
    __syncthreads();
    int rpb = blockDim.x / M;
    int r = blockIdx.x * rpb + threadIdx.x / M;
    int m = threadIdx.x % M;
    if (r >= n) return;
    const float* xr = X + (size_t)r * K;
    float acc = 0.f;
    for (int k = 0; k < K; k++) acc += xr[k] * Wl[k * M + m];
    out[(size_t)r * M + m] = acc;
}

// ---------------- layer-2/3 GEMM with fused BN0 on the input ----------------
// X = raw agg1 output [n,64]; BN params derived inline from sA sums.
// out[n,128] = BN(X) @ [Wm|Ws]
__global__ void k_mm2bn(const float* __restrict__ X,
                        const float* __restrict__ sums,      // sA: [0:64] sum, [64:128] sum2
                        const float* __restrict__ g0, const float* __restrict__ be0,
                        const float* __restrict__ Wa, const float* __restrict__ Wb,
                        float* __restrict__ out, int n) {
    __shared__ float Wl[64 * 128];
    __shared__ float bna[64], bnc[64];
    __shared__ float xs[2 * 64];
    int t = threadIdx.x;
    for (int idx = t; idx < 64 * 128; idx += 256) {
        int k = idx >> 7, m = idx & 127;
        Wl[idx] = (m < 64) ? Wa[k * 64 + m] : Wb[k * 64 + (m - 64)];
    }
    if (t < 64) {
        float mu = sums[t] / n;
        float var = sums[64 + t] / n - mu * mu;
        float a = rsqrtf(var + BN_EPS) * g0[t];
        bna[t] = a;
        bnc[t] = be0[t] - mu * a;
    }
    __syncthreads();
    if (t < 128) {
        int rr = t >> 6, k = t & 63;
        xs[rr * 64 + k] = X[(size_t)(blockIdx.x * 2 + rr) * 64 + k] * bna[k] + bnc[k];
    }
    __syncthreads();
    int r_loc = t >> 7, m = t & 127;
    int r = blockIdx.x * 2 + r_loc;
    float acc = 0.f;
    for (int k = 0; k < 64; k++) acc += xs[r_loc * 64 + k] * Wl[k * 128 + m];
    out[(size_t)r * 128 + m] = acc;
}

// ---------------- GCN aggregation + bias + sigmoid ----------------
__global__ void k_agg(const float* __restrict__ h, const float* __restrict__ dis,
                      const int* __restrict__ offs, const int* __restrict__ ssrc,
                      const float* __restrict__ ba, const float* __restrict__ bb, int Ma,
                      float* __restrict__ out, int dim, int n) {
    int t = blockIdx.x * blockDim.x + threadIdx.x;
    int node = t / dim;
    if (node >= n) return;
    int f = t - node * dim;
    float di = dis[node];
    float acc = h[(size_t)node * dim + f] * di;
    int e0 = offs[node], e1 = offs[node + 1];
    int j = e0;
    for (; j + 3 < e1; j += 4) {
        int s0 = ssrc[j], s1 = ssrc[j + 1], s2 = ssrc[j + 2], s3 = ssrc[j + 3];
        acc += h[(size_t)s0 * dim + f] * dis[s0];
        acc += h[(size_t)s1 * dim + f] * dis[s1];
        acc += h[(size_t)s2 * dim + f] * dis[s2];
        acc += h[(size_t)s3 * dim + f] * dis[s3];
    }
    for (; j < e1; j++) {
        int s = ssrc[j];
        acc += h[(size_t)s * dim + f] * dis[s];
    }
    float bias = (f < Ma) ? ba[f] : bb[f - Ma];
    out[(size_t)node * dim + f] = sigmoidf(acc * di + bias);
}

// ---------------- BatchNorm stats: per-block partials + atomic finalize ----------------
#define STATS_BLOCKS 64
__global__ void k_stats1(const float* __restrict__ act, int dim, int n,
                         float* __restrict__ sums) {   // sums[0:dim]=sum, [dim:2dim]=sum2
    int rpb = 256 / dim;                 // rows per iteration per block (4 or 2)
    int c = threadIdx.x % dim;
    int rloc = threadIdx.x / dim;
    float s = 0.f, s2 = 0.f;
    for (int r = blockIdx.x * rpb + rloc; r < n; r += STATS_BLOCKS * rpb) {
        float v = act[(size_t)r * dim + c];
        s += v; s2 += v * v;
    }
    __shared__ float sh[512];
    sh[threadIdx.x] = s; sh[256 + threadIdx.x] = s2;
    __syncthreads();
    if (rloc == 0) {
        for (int q = 1; q < rpb; q++) {
            s += sh[q * dim + c];
            s2 += sh[256 + q * dim + c];
        }
        atomicAdd(&sums[c], s);
        atomicAdd(&sums[dim + c], s2);
    }
}

// ---------------- fused BN(mean/logstd) + reparam + decoder MLP + zh/zl emit --------
// One block per 16 rows. act2 = raw agg2 output [n,128].
__global__ void k_zdec(const float* __restrict__ act2, const float* __restrict__ noise,
                       const float* __restrict__ sums,   // sB: [0:128] sum, [128:256] sum2
                       const float* __restrict__ gm, const float* __restrict__ bem,
                       const float* __restrict__ gs, const float* __restrict__ bes,
                       const float* __restrict__ W1, const float* __restrict__ B1,
                       const float* __restrict__ W2, const float* __restrict__ B2,
                       unsigned short* __restrict__ zh, unsigned short* __restrict__ zl,
                       float* __restrict__ out, int n) {
    __shared__ float w1[64 * 64];
    __shared__ float w2[64 * 128];
    __shared__ float zs[16 * 64];
    __shared__ float hl[16 * 64];
    __shared__ float bnS[128], bnC[128];
    int t = threadIdx.x;
    int row0 = blockIdx.x * 16;
    {
        const float4* W14 = (const float4*)W1;
        const float4* W24 = (const float4*)W2;
        for (int i = t; i < 1024; i += 256) ((float4*)w1)[i] = W14[i];
        for (int i = t; i < 2048; i += 256) ((float4*)w2)[i] = W24[i];
    }
    if (t < 128) {
        float mu = sums[t] / n;
        float var = sums[128 + t] / n - mu * mu;
        float rs = rsqrtf(var + BN_EPS);
        float g  = (t < 64) ? gm[t] : gs[t - 64];
        float be = (t < 64) ? bem[t] : bes[t - 64];
        float a = rs * g;
        bnS[t] = a;
        bnC[t] = be - mu * a;
    }
    __syncthreads();
    // z for 16x64 elements; 4 per thread
    {
        int base = t * 4;
        int row = base >> 6, j0 = base & 63;
        const float* ar = act2 + (size_t)(row0 + row) * 128;
        const float* nr = noise + (size_t)(row0 + row) * 64;
#pragma unroll
        for (int q = 0; q < 4; q++) {
            int j = j0 + q;
            float m  = ar[j]      * bnS[j]      + bnC[j];
            float ls = ar[64 + j] * bnS[64 + j] + bnC[64 + j];
            float zv = nr[j] * __expf(ls) + m;
            zs[row * 64 + j] = zv;
            unsigned short h = f2bf_rne(zv);
            size_t gi = (size_t)(row0 + row) * 64 + j;
            zh[gi] = h;
            zl[gi] = f2bf_rne(zv - bf2f(h));
        }
    }
    __syncthreads();
    {
        int hc = t & 63, rg = t >> 6;      // 4 rows per thread
        float a0 = B1[hc], a1 = a0, a2 = a0, a3 = a0;
        int rb = rg * 4;
        for (int k = 0; k < 64; k++) {
            float wv = w1[k * 64 + hc];
            a0 += zs[(rb + 0) * 64 + k] * wv;
            a1 += zs[(rb + 1) * 64 + k] * wv;
            a2 += zs[(rb + 2) * 64 + k] * wv;
            a3 += zs[(rb + 3) * 64 + k] * wv;
        }
        hl[(rb + 0) * 64 + hc] = a0 > 0.f ? a0 : 0.01f * a0;
        hl[(rb + 1) * 64 + hc] = a1 > 0.f ? a1 : 0.01f * a1;
        hl[(rb + 2) * 64 + hc] = a2 > 0.f ? a2 : 0.01f * a2;
        hl[(rb + 3) * 64 + hc] = a3 > 0.f ? a3 : 0.01f * a3;
    }
    __syncthreads();
    {
        int oc = t & 127, rg = t >> 7;     // 8 rows per thread
        float o[8];
#pragma unroll
        for (int i = 0; i < 8; i++) o[i] = B2[oc];
        int rb = rg * 8;
        for (int k = 0; k < 64; k++) {
            float wv = w2[k * 128 + oc];
#pragma unroll
            for (int i = 0; i < 8; i++) o[i] += hl[(rb + i) * 64 + k] * wv;
        }
#pragma unroll
        for (int i = 0; i < 8; i++)
            out[(size_t)(row0 + rb + i) * 128 + oc] = o[i];
    }
}

// ---------------- A_pred = sigmoid(z @ z^T) via bf16 hi/lo split MFMA ----------------
// Full 94x94 block grid; LDS-staged XOR-swizzled tiles; coalesced nontemporal stores.
#define TN2 94   // ceil(12000/128); 94*128 = 12032 = padded row count
__global__ __launch_bounds__(256, 2) void k_apred(const unsigned short* __restrict__ zh,
                                                  const unsigned short* __restrict__ zl,
                                                  float* __restrict__ out, int n) {
    __shared__ __align__(16) unsigned short si_h[128 * 64];
    __shared__ __align__(16) unsigned short si_l[128 * 64];
    __shared__ __align__(16) unsigned short sj_h[128 * 64];
    __shared__ __align__(16) unsigned short sj_l[128 * 64];

    int bj = blockIdx.x, bi = blockIdx.y;
    int i0 = bi * 128, j0 = bj * 128;
    int t = threadIdx.x;

    auto stage = [&](const unsigned short* __restrict__ g, unsigned short* s, int row0) {
#pragma unroll
        for (int q = 0; q < 4; q++) {
            int u = q * 256 + t;
            int row = u >> 3, c16 = u & 7;
            int c16s = c16 ^ (row & 7);
            *(float4*)((char*)s + row * 128 + c16s * 16) =
                *(const float4*)(g + (size_t)(row0 + row) * 64 + c16 * 8);
        }
    };
    stage(zh, si_h, i0);
    stage(zl, si_l, i0);
    stage(zh, sj_h, j0);
    stage(zl, sj_l, j0);
    __syncthreads();

    int wave = t >> 6, lane = t & 63;
    int wr = wave >> 1, wc = wave & 1;
    int lrow = lane & 15;   // row (A) / col (B) within fragment
    int kg   = lane >> 4;   // k-group 0..3

    auto frag = [&](const unsigned short* s, int tr, int kc) -> bf16x8 {
        int c16s = (kc * 4 + kg) ^ (tr & 7);
        return *(const bf16x8*)((const char*)s + tr * 128 + c16s * 16);
    };

    f32x4 acc[4][4] = {};

#pragma unroll
    for (int kc = 0; kc < 2; kc++) {
        bf16x8 ah[4], al[4], bh[4], bl[4];
#pragma unroll
        for (int f = 0; f < 4; f++) {
            int tra = wr * 64 + f * 16 + lrow;
            ah[f] = frag(si_h, tra, kc);
            al[f] = frag(si_l, tra, kc);
            int trb = wc * 64 + f * 16 + lrow;
            bh[f] = frag(sj_h, trb, kc);
            bl[f] = frag(sj_l, trb, kc);
        }
#pragma unroll
        for (int fi = 0; fi < 4; fi++)
#pragma unroll
            for (int fj = 0; fj < 4; fj++) {
                acc[fi][fj] = __builtin_amdgcn_mfma_f32_16x16x32_bf16(
                    ah[fi], bh[fj], acc[fi][fj], 0, 0, 0);
                acc[fi][fj] = __builtin_amdgcn_mfma_f32_16x16x32_bf16(
                    ah[fi], bl[fj], acc[fi][fj], 0, 0, 0);
                acc[fi][fj] = __builtin_amdgcn_mfma_f32_16x16x32_bf16(
                    al[fi], bh[fj], acc[fi][fj], 0, 0, 0);
            }
    }

#pragma unroll
    for (int fi = 0; fi < 4; fi++)
#pragma unroll
        for (int fj = 0; fj < 4; fj++)
#pragma unroll
            for (int q = 0; q < 4; q++)
                acc[fi][fj][q] = sigmoidf(acc[fi][fj][q]);

    int colb = j0 + wc * 64;
#pragma unroll
    for (int fi = 0; fi < 4; fi++) {
#pragma unroll
        for (int q = 0; q < 4; q++) {
            int r = i0 + wr * 64 + fi * 16 + kg * 4 + q;
            if (r < n) {
                float* orow = out + (size_t)r * n + colb;
#pragma unroll
                for (int fj = 0; fj < 4; fj++) {
                    int c = fj * 16 + lrow;
                    if (colb + c < n)
                        __builtin_nontemporal_store(acc[fi][fj][q], &orow[c]);
                }
            }
        }
    }
}

extern "C" void kernel_launch(void* const* d_in, const int* in_sizes, int n_in,
                              void* d_out, int out_size, void* d_ws, size_t ws_size,
                              hipStream_t stream) {
    const float* x     = (const float*)d_in[0];
    const int*   src   = (const int*)d_in[1];
    const int*   dst   = (const int*)d_in[2];
    const float* noise = (const float*)d_in[4];
    const float* W0  = (const float*)d_in[5];
    const float* b0  = (const float*)d_in[6];
    const float* g0  = (const float*)d_in[7];
    const float* be0 = (const float*)d_in[8];
    const float* Wm  = (const float*)d_in[9];
    const float* bm  = (const float*)d_in[10];
    const float* gm  = (const float*)d_in[11];
    const float* bem = (const float*)d_in[12];
    const float* Ws  = (const float*)d_in[13];
    const float* bs  = (const float*)d_in[14];
    const float* gs  = (const float*)d_in[15];
    const float* bes = (const float*)d_in[16];
    const float* Dw1 = (const float*)d_in[17];
    const float* Db1 = (const float*)d_in[18];
    const float* Dw2 = (const float*)d_in[19];
    const float* Db2 = (const float*)d_in[20];
    float* out = (float*)d_out;

    const int n = N_NODES, e = N_EDGES;

    // workspace layout (4-byte words)
    int*   cnt  = (int*)d_ws;                       // 12000
    int*   offs = (int*)d_ws + 12032;               // 12001
    int*   cur  = (int*)d_ws + 24064;               // 12000
    int*   ssrc = (int*)d_ws + 36096;               // 384000
    float* dis  = (float*)d_ws + 420096;            // 12000
    float* sA   = (float*)d_ws + 432128;            // 128 (sum 64 + sum2 64)
    float* sB   = (float*)d_ws + 432384;            // 256 (sum 128 + sum2 128)
    float* bufA = (float*)d_ws + 449024;            // [N,128]
    float* bufB = bufA + (size_t)N_NODES * 128;     // [N,128]
    // bf16 hi/lo split of z, padded to 12032 rows (16B-aligned)
    unsigned short* zhbuf = (unsigned short*)((float*)d_ws + 3521024); // 12032*64 ushort
    unsigned short* zlbuf = (unsigned short*)((float*)d_ws + 3906048); // 12032*64 ushort

    // CSR build (+ zero stat accumulators, zh/zl pad rows)
    k_init<<<(n + 255) / 256, 256, 0, stream>>>(cnt, cur, sA, sB, zhbuf, zlbuf, n);
    k_count<<<(e + 255) / 256, 256, 0, stream>>>(dst, cnt, e);
    k_scan<<<1, 1024, 0, stream>>>(cnt, offs, dis, n);
    k_scatter<<<(e + 255) / 256, 256, 0, stream>>>(src, dst, offs, cur, ssrc, e);

    // layer 1: GEMM -> aggregate+sigmoid -> stats (atomic finalize)
    k_mm<<<n / 4, 256, 0, stream>>>(x, n, F_INN, W0, DLAT, nullptr, 0, bufA);
    k_agg<<<(n * DLAT) / 256, 256, 0, stream>>>(bufA, dis, offs, ssrc, b0, nullptr, DLAT,
                                                bufB, DLAT, n);
    k_stats1<<<STATS_BLOCKS, 256, 0, stream>>>(bufB, DLAT, n, sA);

    // layers 2+3: BN0 fused into GEMM load -> aggregate+sigmoid -> stats
    k_mm2bn<<<n / 2, 256, 0, stream>>>(bufB, sA, g0, be0, Wm, Ws, bufA, n);
    k_agg<<<(n * 128) / 256, 256, 0, stream>>>(bufA, dis, offs, ssrc, bm, bs, DLAT,
                                               bufB, 128, n);
    k_stats1<<<STATS_BLOCKS, 256, 0, stream>>>(bufB, 128, n, sB);

    // fused BN + reparam + decoder (emits zh/zl for apred, z never hits HBM)
    k_zdec<<<n / 16, 256, 0, stream>>>(bufB, noise, sB, gm, bem, gs, bes,
                                       Dw1, Db1, Dw2, Db2, zhbuf, zlbuf, out, n);

    // A_pred (full grid, coalesced nontemporal stores)
    {
        dim3 grid(TN2, TN2);
        k_apred<<<grid, 256, 0, stream>>>(zhbuf, zlbuf, out + (size_t)n * F_INN, n);
    }
}